// Round 2
// baseline (85076.294 us; speedup 1.0000x reference)
//
#include <hip/hip_runtime.h>
#include <cstdint>
#include <cstddef>

#define T_ 512
#define B_ 32
#define D_ 1024
#define L_ 4
#define BD_ (B_*D_)
#define LBD_ (L_*BD_)
#define NWG 16
#define TPB 256
#define EPSF 1e-5f

typedef _Float16 f16x8 __attribute__((ext_vector_type(8)));
typedef float f32x4 __attribute__((ext_vector_type(4)));

// workspace layout (bytes)
#define WS_BAR    0
#define WS_YSTAT  64
#define WS_STATE1 4096
#define WS_WT     (1u<<20)

// LDS layout (bytes)
#define LDS_A     0          // 32 rows x 2048 fused-k fp16, row stride 4096B, XOR-swizzled
#define LDS_DUMP  131072     // 16 tile-slots x 64 lanes x 16B
#define LDS_PART  147456     // 32 x 8 float2
#define LDS_LN    149504     // 32 float2 (mean, rstd)
#define LDS_YS    149760     // 32 float2 (sum, sumsq)
#define LDS_TOTAL 150528

__device__ __forceinline__ unsigned pk2h(float a, float b){
  _Float16 ha = (_Float16)a, hb = (_Float16)b;
  unsigned short ua = __builtin_bit_cast(unsigned short, ha);
  unsigned short ub = __builtin_bit_cast(unsigned short, hb);
  return (unsigned)ua | ((unsigned)ub<<16);
}
__device__ __forceinline__ f16x8 as_h(uint4 u){ return __builtin_bit_cast(f16x8, u); }

__device__ __forceinline__ void gbar(unsigned* bar){
  __threadfence();          // release: flush this wave's stores (per-wave, before join)
  __syncthreads();          // all waves' fences done before arrival
  if (threadIdx.x == 0){
    unsigned old = __hip_atomic_fetch_add(bar, 1u, __ATOMIC_RELAXED, __HIP_MEMORY_SCOPE_AGENT);
    unsigned tgt = (old/NWG + 1u) * (unsigned)NWG;
    while (__hip_atomic_load(bar, __ATOMIC_RELAXED, __HIP_MEMORY_SCOPE_AGENT) < tgt){
      __builtin_amdgcn_s_sleep(2);
    }
  }
  __syncthreads();
  __threadfence();          // acquire: invalidate stale lines before next phase's reads
}

// ---------------- pre-pass: fp32 (D,D) row-major -> fp16 transposed fused layout ----------------
// WT flat index: ((i*2048 + c)*2 + ks)*1024 + k   [ushorts]
//   c < 1024 : f-gate col c ;  c >= 1024 : cand col c-1024
//   ks = 0   : W (hn half)  ;  ks = 1    : U (state half)
extern "C" __global__ void __launch_bounds__(256,1) crs_prepass(
    const float* __restrict__ Wf, const float* __restrict__ Uf,
    const float* __restrict__ Wc, const float* __restrict__ Uc,
    unsigned short* __restrict__ WT)
{
  int bid = blockIdx.x;              // (((i*4+sel)*32+ct)*16+kt)
  int kt  = bid & 15;
  int ct  = (bid>>4) & 31;
  int sel = (bid>>9) & 3;            // 0=Wf 1=Uf 2=Wc 3=Uc
  int i   = bid >> 11;
  int tid = threadIdx.x;
  int kq  = tid >> 5;                // 0..7
  int cc  = tid & 31;                // 0..31
  const float* sp;
  if      (sel==0) sp = Wf;
  else if (sel==1) sp = Uf;
  else if (sel==2) sp = Wc;
  else             sp = Uc;
  sp += (size_t)i * 1048576;
  int cl = ct*32 + cc;
  int k0 = kt*64 + kq*8;
  float f[8];
  #pragma unroll
  for (int e=0;e<8;++e){ f[e] = sp[(size_t)(k0+e)*1024 + cl]; }
  int cg = ((sel>>1) ? 1024 : 0) + cl;
  int ks = sel & 1;
  size_t idx = ((size_t)(i*2048 + cg)*2 + ks)*1024 + k0;
  uint4 pk;
  pk.x = pk2h(f[0], f[1]);
  pk.y = pk2h(f[2], f[3]);
  pk.z = pk2h(f[4], f[5]);
  pk.w = pk2h(f[6], f[7]);
  *(uint4*)(WT + idx) = pk;
}

// ---------------- main persistent kernel ----------------
extern "C" __global__ void __launch_bounds__(TPB,1) crs_main(
    const float* __restrict__ x,
    const float* __restrict__ bfv, const float* __restrict__ bcv,
    const float* __restrict__ pg,  const float* __restrict__ pb,
    const float* __restrict__ sg,  const float* __restrict__ sbv,
    float* __restrict__ y, float* __restrict__ ostate, float* __restrict__ state1,
    const unsigned short* __restrict__ WT,
    unsigned* __restrict__ bar, float* __restrict__ ystat)
{
  extern __shared__ char smem[];
  const int tid  = threadIdx.x;
  const int w    = blockIdx.x;       // 0..15, owns ns-cols [w*64, w*64+64)
  const int lane = tid & 63;
  const int v    = tid >> 6;         // wave id
  const int kh   = v & 1;            // 0: hn*W half, 1: s*U half
  const int ch   = v >> 1;           // column-pair group
  const int l15  = lane & 15;
  const int lg   = lane >> 4;        // 0..3
  const int sw   = (l15 & 7) << 4;   // XOR swizzle for A reads (rows l15 and 16+l15 share it)
  const int r    = tid >> 3;         // staging row 0..31
  const int seg  = tid & 7;          // staging k-segment
  const int swr  = (r & 7) << 4;     // XOR swizzle for A writes

  #pragma unroll 1
  for (int t=0; t<T_; ++t){
    float* scur = (t & 1) ? state1 : ostate;
    float* snxt = (t & 1) ? ostate : state1;
    #pragma unroll 1
    for (int i=0; i<L_; ++i){
      // ---- stack-LN output y[t-1] (stats accumulated during previous step's layer-3 phase)
      if (i==0 && t>0){
        const float* h3 = scur + 3*(size_t)BD_;
        int b = tid>>3, c8 = (tid&7)*8;
        int col = w*64 + c8;
        float s0 = ystat[2*b], q0 = ystat[2*b+1];
        float m  = s0*(1.f/1024.f);
        float var = q0*(1.f/1024.f) - m*m;
        float rs = rsqrtf(var + EPSF);
        const float4* hp4 = (const float4*)(h3 + (size_t)b*D_ + col);
        const float4* sg4 = (const float4*)(sg + col);
        const float4* sb4 = (const float4*)(sbv + col);
        float4* yp4 = (float4*)(y + (size_t)(t-1)*BD_ + (size_t)b*D_ + col);
        #pragma unroll
        for (int q=0;q<2;++q){
          float4 hh = hp4[q], gg = sg4[q], bb = sb4[q];
          float4 o;
          o.x = (hh.x-m)*rs*gg.x + bb.x;
          o.y = (hh.y-m)*rs*gg.y + bb.y;
          o.z = (hh.z-m)*rs*gg.z + bb.z;
          o.w = (hh.w-m)*rs*gg.w + bb.w;
          yp4[q] = o;
        }
      }

      // ---- A staging: LN(h) into fused-k [0,1024), state into [1024,2048), fp16, swizzled
      const float* hsrc = (i==0) ? (x + (size_t)t*BD_) : (snxt + (size_t)(i-1)*BD_);
      const float* ssrc = scur + (size_t)i*BD_;
      const float4* hv = (const float4*)(hsrc + (size_t)r*D_ + seg*128);
      float sum=0.f, sq=0.f;
      #pragma unroll 8
      for (int q=0;q<32;++q){
        float4 h4 = hv[q];
        sum += h4.x + h4.y + h4.z + h4.w;
        sq  += h4.x*h4.x + h4.y*h4.y + h4.z*h4.z + h4.w*h4.w;
      }
      ((float2*)(smem+LDS_PART))[r*8+seg] = make_float2(sum, sq);
      if (tid < 64) ((float*)(smem+LDS_YS))[tid] = 0.f;
      __syncthreads();
      if (tid < 32){
        const float2* pp = (const float2*)(smem+LDS_PART) + tid*8;
        float s1=0.f, q1=0.f;
        #pragma unroll
        for (int e=0;e<8;++e){ s1 += pp[e].x; q1 += pp[e].y; }
        float m = s1*(1.f/1024.f);
        float var = q1*(1.f/1024.f) - m*m;
        ((float2*)(smem+LDS_LN))[tid] = make_float2(m, rsqrtf(var+EPSF));
      }
      __syncthreads();
      {
        float2 mr = ((const float2*)(smem+LDS_LN))[r];
        const float m = mr.x, rs = mr.y;
        const float4* gv = (const float4*)(pg + (size_t)i*D_ + seg*128);
        const float4* bv = (const float4*)(pb + (size_t)i*D_ + seg*128);
        #pragma unroll 4
        for (int jj=0;jj<16;++jj){
          float4 h0 = hv[2*jj], h1 = hv[2*jj+1];
          float4 g0 = gv[2*jj], g1 = gv[2*jj+1];
          float4 p0 = bv[2*jj], p1 = bv[2*jj+1];
          float n0 = (h0.x-m)*rs*g0.x + p0.x;
          float n1 = (h0.y-m)*rs*g0.y + p0.y;
          float n2 = (h0.z-m)*rs*g0.z + p0.z;
          float n3 = (h0.w-m)*rs*g0.w + p0.w;
          float n4 = (h1.x-m)*rs*g1.x + p1.x;
          float n5 = (h1.y-m)*rs*g1.y + p1.y;
          float n6 = (h1.z-m)*rs*g1.z + p1.z;
          float n7 = (h1.w-m)*rs*g1.w + p1.w;
          uint4 pk;
          pk.x = pk2h(n0, n1);
          pk.y = pk2h(n2, n3);
          pk.z = pk2h(n4, n5);
          pk.w = pk2h(n6, n7);
          int fkb = (seg*128 + jj*8)*2;
          *(uint4*)(smem + LDS_A + (size_t)r*4096 + (fkb ^ swr)) = pk;
        }
        const float4* sv = (const float4*)(ssrc + (size_t)r*D_ + seg*128);
        #pragma unroll 4
        for (int jj=0;jj<16;++jj){
          float4 s0 = sv[2*jj], s1v = sv[2*jj+1];
          uint4 pk;
          pk.x = pk2h(s0.x,  s0.y);
          pk.y = pk2h(s0.z,  s0.w);
          pk.z = pk2h(s1v.x, s1v.y);
          pk.w = pk2h(s1v.z, s1v.w);
          int fkb = 2048 + (seg*128 + jj*8)*2;
          *(uint4*)(smem + LDS_A + (size_t)r*4096 + (fkb ^ swr)) = pk;
        }
      }
      __syncthreads();

      // ---- MFMA k-loop: wave (kh,ch); acc[rowtile][g*2+cp]
      f32x4 acc[2][4];
      #pragma unroll
      for (int a1=0;a1<2;++a1){
        #pragma unroll
        for (int a2=0;a2<4;++a2){ acc[a1][a2] = (f32x4){0.f,0.f,0.f,0.f}; }
      }
      const unsigned short *pB0, *pB1, *pB2, *pB3;
      {
        size_t base = (size_t)i*2048;
        size_t koff = (size_t)kh*1024 + (size_t)lg*8;
        int c0 =        w*64 + (2*ch+0)*16 + l15;
        int c1 =        w*64 + (2*ch+1)*16 + l15;
        int c2 = 1024 + w*64 + (2*ch+0)*16 + l15;
        int c3 = 1024 + w*64 + (2*ch+1)*16 + l15;
        pB0 = WT + ((base + c0)*2048 + koff);
        pB1 = WT + ((base + c1)*2048 + koff);
        pB2 = WT + ((base + c2)*2048 + koff);
        pB3 = WT + ((base + c3)*2048 + koff);
      }
      const char* A0 = smem + LDS_A + (size_t)l15*4096;
      const char* A1 = smem + LDS_A + (size_t)(16+l15)*4096;
      #pragma unroll 4
      for (int j=0;j<32;++j){
        int fkb = kh*2048 + j*64 + lg*16;
        int fo  = fkb ^ sw;
        f16x8 a0 = as_h(*(const uint4*)(A0 + fo));
        f16x8 a1 = as_h(*(const uint4*)(A1 + fo));
        f16x8 b0 = as_h(*(const uint4*)(pB0 + j*32));
        f16x8 b1 = as_h(*(const uint4*)(pB1 + j*32));
        f16x8 b2 = as_h(*(const uint4*)(pB2 + j*32));
        f16x8 b3 = as_h(*(const uint4*)(pB3 + j*32));
        acc[0][0] = __builtin_amdgcn_mfma_f32_16x16x32_f16(a0, b0, acc[0][0], 0,0,0);
        acc[1][0] = __builtin_amdgcn_mfma_f32_16x16x32_f16(a1, b0, acc[1][0], 0,0,0);
        acc[0][1] = __builtin_amdgcn_mfma_f32_16x16x32_f16(a0, b1, acc[0][1], 0,0,0);
        acc[1][1] = __builtin_amdgcn_mfma_f32_16x16x32_f16(a1, b1, acc[1][1], 0,0,0);
        acc[0][2] = __builtin_amdgcn_mfma_f32_16x16x32_f16(a0, b2, acc[0][2], 0,0,0);
        acc[1][2] = __builtin_amdgcn_mfma_f32_16x16x32_f16(a1, b2, acc[1][2], 0,0,0);
        acc[0][3] = __builtin_amdgcn_mfma_f32_16x16x32_f16(a0, b3, acc[0][3], 0,0,0);
        acc[1][3] = __builtin_amdgcn_mfma_f32_16x16x32_f16(a1, b3, acc[1][3], 0,0,0);
      }
      __syncthreads();
      if (kh==1){
        #pragma unroll
        for (int rt=0;rt<2;++rt){
          #pragma unroll
          for (int tf=0;tf<4;++tf){
            *(f32x4*)(smem + LDS_DUMP + ((((ch*2+rt)*4+tf)*64 + lane)<<4)) = acc[rt][tf];
          }
        }
      }
      __syncthreads();
      if (kh==0){
        #pragma unroll
        for (int rt=0;rt<2;++rt){
          #pragma unroll
          for (int tf=0;tf<4;++tf){
            acc[rt][tf] += *(const f32x4*)(smem + LDS_DUMP + ((((ch*2+rt)*4+tf)*64 + lane)<<4));
          }
        }
        // epilogue: bias + sigmoid/tanh + state EMA (fp32 master state)
        const size_t sbi = (size_t)i*BD_;
        #pragma unroll
        for (int rt=0;rt<2;++rt){
          #pragma unroll
          for (int cp=0;cp<2;++cp){
            f32x4 f4 = acc[rt][cp];
            f32x4 c4 = acc[rt][2+cp];
            int colb = w*64 + (2*ch+cp)*16 + l15;
            float bfs = bfv[(size_t)i*D_ + colb];
            float bcs = bcv[(size_t)i*D_ + colb];
            #pragma unroll
            for (int jj=0;jj<4;++jj){
              int b = rt*16 + lg*4 + jj;
              float preF = f4[jj] + bfs;
              float preC = c4[jj] + bcs;
              preF = fminf(fmaxf(preF, -30.f), 30.f);
              preC = fminf(fmaxf(preC, -30.f), 30.f);
              float fg = 1.f/(1.f + __expf(-preF));
              float e2 = __expf(-2.f*preC);
              float cd = (1.f - e2)/(1.f + e2);
              float sold = scur[sbi + (size_t)b*D_ + colb];
              float ns = fg*sold + (1.f-fg)*cd;
              snxt[sbi + (size_t)b*D_ + colb] = ns;
              if (i==3){
                atomicAdd(((float*)(smem+LDS_YS)) + 2*b,     ns);
                atomicAdd(((float*)(smem+LDS_YS)) + 2*b + 1, ns*ns);
              }
            }
          }
        }
      }
      __syncthreads();
      if (i==3 && tid<32){
        float* yl = (float*)(smem+LDS_YS);
        atomicAdd(ystat + 2*tid,     yl[2*tid]);
        atomicAdd(ystat + 2*tid + 1, yl[2*tid+1]);
      }
      if (i==1 && w==0 && tid<64) ystat[tid] = 0.f;
      gbar(bar);
    }
  }

  // ---- final y[511] (stats from t=511 layer-3, final h3 = ostate row 3)
  {
    const float* h3 = ostate + 3*(size_t)BD_;
    int b = tid>>3, c8 = (tid&7)*8;
    int col = w*64 + c8;
    float s0 = ystat[2*b], q0 = ystat[2*b+1];
    float m  = s0*(1.f/1024.f);
    float var = q0*(1.f/1024.f) - m*m;
    float rs = rsqrtf(var + EPSF);
    const float4* hp4 = (const float4*)(h3 + (size_t)b*D_ + col);
    const float4* sg4 = (const float4*)(sg + col);
    const float4* sb4 = (const float4*)(sbv + col);
    float4* yp4 = (float4*)(y + (size_t)511*BD_ + (size_t)b*D_ + col);
    #pragma unroll
    for (int q=0;q<2;++q){
      float4 hh = hp4[q], gg = sg4[q], bb = sb4[q];
      float4 o;
      o.x = (hh.x-m)*rs*gg.x + bb.x;
      o.y = (hh.y-m)*rs*gg.y + bb.y;
      o.z = (hh.z-m)*rs*gg.z + bb.z;
      o.w = (hh.w-m)*rs*gg.w + bb.w;
      yp4[q] = o;
    }
  }
}

extern "C" void kernel_launch(void* const* d_in, const int* in_sizes, int n_in,
                              void* d_out, int out_size, void* d_ws, size_t ws_size,
                              hipStream_t stream){
  (void)in_sizes; (void)n_in; (void)out_size; (void)ws_size;
  const float* x   = (const float*)d_in[0];
  const float* st0 = (const float*)d_in[1];
  const float* Wf  = (const float*)d_in[2];
  const float* Uf  = (const float*)d_in[3];
  const float* bfv = (const float*)d_in[4];
  const float* Wc  = (const float*)d_in[5];
  const float* Uc  = (const float*)d_in[6];
  const float* bcv = (const float*)d_in[7];
  const float* pg  = (const float*)d_in[8];
  const float* pb  = (const float*)d_in[9];
  const float* sg  = (const float*)d_in[10];
  const float* sbv = (const float*)d_in[11];

  float* y      = (float*)d_out;
  float* ostate = y + (size_t)T_*BD_;

  char* ws = (char*)d_ws;
  unsigned* bar        = (unsigned*)(ws + WS_BAR);
  float* ystat         = (float*)(ws + WS_YSTAT);
  float* state1        = (float*)(ws + WS_STATE1);
  unsigned short* WT   = (unsigned short*)(ws + WS_WT);

  hipMemsetAsync(ws, 0, 4096, stream);
  hipMemcpyAsync(ostate, st0, sizeof(float)*(size_t)LBD_, hipMemcpyDeviceToDevice, stream);
  hipLaunchKernelGGL(crs_prepass, dim3(8192), dim3(256), 0, stream, Wf, Uf, Wc, Uc, WT);
  hipFuncSetAttribute((const void*)crs_main, hipFuncAttributeMaxDynamicSharedMemorySize, LDS_TOTAL);
  hipLaunchKernelGGL(crs_main, dim3(NWG), dim3(TPB), LDS_TOTAL, stream,
                     x, bfv, bcv, pg, pb, sg, sbv, y, ostate, state1, WT, bar, ystat);
}